// Round 3
// baseline (1162.968 us; speedup 1.0000x reference)
//
#include <hip/hip_runtime.h>

// Problem constants (fixed by the reference setup_inputs).
constexpr int B_ = 1024;
constexpr int S_ = 200;
constexpr int Q_ = 512;
constexpr int TQ = 2 * Q_;              // 1024 floats per batch row
constexpr int SM1 = S_ - 1;             // 199
constexpr int ROWS = B_ * SM1;          // 203,776 (b, t=i+1) rows to scan

constexpr int BLOCK = 256;              // 4 waves/block
constexpr int GRID  = 2048;
constexpr int WAVES = GRID * (BLOCK / 64);   // 8192 waves = 32/CU (full occupancy)

constexpr int MLP = 4;                  // rows scanned concurrently per wave
// rows/wave = ceil(203776/8192) = 25 -> round up to multiple of MLP
constexpr int KMAX = (((ROWS + WAVES - 1) / WAVES) + MLP - 1) / MLP * MLP;  // 28

// One wave scans MLP=4 one-hot rows concurrently in 512-byte chunks
// (64 lanes x float2, coalesced), wave-uniform ballot early-exit per row.
//   Expected traffic: 512B * 4.1 chunks = 2.05 KB/row (vs 4 KB full read).
//   In-flight: up to 4 x 512B per wave -> 16 MB aggregate across 8192 waves,
//   above the ~5 MB BW*latency product -> bandwidth-bound, not latency-bound
//   (round-1's single-row chunk chain had only 4 MB in flight and stalled).
//   Serial RT depth/wave: 7 groups x E[max chunks of 4 rows]=6.5 ~ 46 RTs
//   x ~400ns ~ 18us << ~70us BW floor.
__global__ __launch_bounds__(BLOCK, 8) void lossFunc_kernel(
    const float* __restrict__ pred,    // [B, S, Q]
    const float* __restrict__ batch,   // [B, S, 2Q]
    float* __restrict__ out)           // [1], pre-zeroed
{
    const int lane = threadIdx.x & 63;
    const int wid  = threadIdx.x >> 6;
    const int gw   = blockIdx.x * (BLOCK / 64) + wid;

    float acc = 0.0f;

    for (int k = 0; k < KMAX; k += MLP) {
        const float2* rp[MLP];
        int  jj[MLP];
        bool found[MLP];
        int  rb[MLP], ri[MLP];

        #pragma unroll
        for (int u = 0; u < MLP; ++u) {
            const int r     = gw + (k + u) * WAVES;   // wave-uniform
            const bool valid = (r < ROWS);
            const int rc    = valid ? r : 0;
            const int b     = rc / SM1;
            const int i     = rc - b * SM1;           // 0..S-2; batch step t=i+1
            rb[u] = b;  ri[u] = i;
            rp[u] = (const float2*)(batch + ((size_t)b * S_ + (i + 1)) * TQ);
            jj[u] = -1;
            found[u] = !valid;                        // invalid rows: never load
        }

        #pragma unroll
        for (int c = 0; c < 8; ++c) {
            float2 v[MLP];
            bool   ld[MLP];
            // Issue all pending loads back-to-back: up to 4 in flight.
            #pragma unroll
            for (int u = 0; u < MLP; ++u) {
                ld[u] = !found[u];                    // wave-uniform
                if (ld[u]) v[u] = rp[u][(c << 6) + lane];
            }
            // Consume in issue order (vmcnt waits release oldest-first).
            #pragma unroll
            for (int u = 0; u < MLP; ++u) {
                if (ld[u]) {
                    const int e = (c << 7) + (lane << 1);
                    if (v[u].x != 0.0f) jj[u] = e;
                    if (v[u].y != 0.0f) jj[u] = e + 1;
                    found[u] = (__ballot(jj[u] >= 0) != 0ULL);
                }
            }
            if (found[0] && found[1] && found[2] && found[3]) break;
        }

        // Exactly one lane per row holds the nonzero.
        #pragma unroll
        for (int u = 0; u < MLP; ++u) {
            if (jj[u] >= 0) {
                const bool corr = (jj[u] < Q_);
                const int  q    = corr ? jj[u] : (jj[u] - Q_);
                const float p   = pred[((size_t)rb[u] * S_ + ri[u]) * Q_ + q];
                if (p > 0.0f) {
                    acc -= corr ? __logf(p) : __logf(1.0f - p);
                }
            }
        }
    }

    // Wave reduction (64 lanes).
    #pragma unroll
    for (int off = 32; off > 0; off >>= 1)
        acc += __shfl_down(acc, off, 64);

    __shared__ float waveSums[BLOCK / 64];
    if (lane == 0) waveSums[wid] = acc;
    __syncthreads();

    if (threadIdx.x == 0) {
        float s = 0.0f;
        #pragma unroll
        for (int w = 0; w < BLOCK / 64; ++w) s += waveSums[w];
        atomicAdd(out, s);
    }
}

extern "C" void kernel_launch(void* const* d_in, const int* in_sizes, int n_in,
                              void* d_out, int out_size, void* d_ws, size_t ws_size,
                              hipStream_t stream) {
    const float* pred  = (const float*)d_in[0];
    const float* batch = (const float*)d_in[1];
    float* out = (float*)d_out;

    // Harness poisons d_out to 0xAA before each call — zero it (capture-safe).
    hipMemsetAsync(out, 0, sizeof(float), stream);

    lossFunc_kernel<<<GRID, BLOCK, 0, stream>>>(pred, batch, out);
}